// Round 1
// baseline (275.985 us; speedup 1.0000x reference)
//
#include <hip/hip_runtime.h>
#include <hip/hip_bf16.h>

typedef __bf16 bf16;
typedef bf16 bf16x2 __attribute__((ext_vector_type(2)));
typedef bf16 bf16x4 __attribute__((ext_vector_type(4)));
typedef bf16 bf16x8 __attribute__((ext_vector_type(8)));
typedef float f32x4 __attribute__((ext_vector_type(4)));

#define HID 1024
#define NHEADS 16
#define HD 64
#define SEQ 4096

__device__ __forceinline__ void gll16(const void* g, void* l) {
  __builtin_amdgcn_global_load_lds(
      (const __attribute__((address_space(1))) void*)g,
      (__attribute__((address_space(3))) void*)l, 16, 0, 0);
}

// ---------------------------------------------------------------------------
// Prep: z=0 convert X fp32->bf16; z=1..4 transpose+convert W -> Wt[out][in],
// folding attention scale (0.125, exact) into Wq.
// ---------------------------------------------------------------------------
__global__ __launch_bounds__(256)
void prep_kernel(const float* __restrict__ X,
                 const float* __restrict__ Wq, const float* __restrict__ Wk,
                 const float* __restrict__ Wv, const float* __restrict__ Wo,
                 bf16* __restrict__ Xb, bf16* __restrict__ Wt)
{
  const int z = blockIdx.z, t = threadIdx.x, bx = blockIdx.x;
  if (z == 0) {
    const float4* src = (const float4*)X;
    const int gid = bx * 256 + t;
    #pragma unroll
    for (int i = 0; i < 16; ++i) {
      float4 v = src[gid + i * 65536];
      bf16x4 o = {(bf16)v.x, (bf16)v.y, (bf16)v.z, (bf16)v.w};
      *(bf16x4*)&Xb[(size_t)(gid + i * 65536) * 4] = o;
    }
  } else {
    const float* W = (z == 1) ? Wq : (z == 2) ? Wk : (z == 3) ? Wv : Wo;
    bf16* dst = Wt + (size_t)(z - 1) * HID * HID;
    const float scale = (z == 1) ? 0.125f : 1.0f;
    __shared__ bf16 T[64][68];
    const int tr = (bx >> 4) * 64, tc = (bx & 15) * 64;
    #pragma unroll
    for (int p = 0; p < 4; ++p) {
      int row = (t >> 4) + p * 16;
      float4 v = *(const float4*)&W[(size_t)(tr + row) * HID + tc + (t & 15) * 4];
      T[row][(t & 15) * 4 + 0] = (bf16)(v.x * scale);
      T[row][(t & 15) * 4 + 1] = (bf16)(v.y * scale);
      T[row][(t & 15) * 4 + 2] = (bf16)(v.z * scale);
      T[row][(t & 15) * 4 + 3] = (bf16)(v.w * scale);
    }
    __syncthreads();
    #pragma unroll
    for (int p = 0; p < 4; ++p) {
      int rp = (t >> 4) + p * 16;
      int cb = (t & 15) * 4;
      bf16x4 o = {T[cb + 0][rp], T[cb + 1][rp], T[cb + 2][rp], T[cb + 3][rp]};
      *(bf16x4*)&dst[(size_t)(tc + rp) * HID + tr + cb] = o;
    }
  }
}

// ---------------------------------------------------------------------------
// QKV GEMM: C = Xb[M,K] @ Wt[z][N,K]^T. 128x128 tile, BK=64, global_load_lds
// staging with chunk-rotation swizzle (row k chunk c -> slot k*8+((c+k)&7))
// so column-of-rows frag reads spread over all 32 banks.
// z=2 writes V transposed (Vt[hid][seq]) via swizzled LDS transpose.
// ---------------------------------------------------------------------------
__global__ __launch_bounds__(256)
void qkv_gemm(const bf16* __restrict__ A, const bf16* __restrict__ Wt,
              bf16* __restrict__ Qg, bf16* __restrict__ Kg,
              bf16* __restrict__ Vt)
{
  __shared__ bf16 sbuf[16384];
  bf16* As = sbuf;
  bf16* Bs = sbuf + 8192;

  const int t = threadIdx.x, lane = t & 63, w = t >> 6;
  const int z = blockIdx.z;
  const int n0 = blockIdx.x * 128, m0 = blockIdx.y * 128;
  const bf16* Bt = Wt + (size_t)z * HID * HID;
  const int wm = (w & 1) * 64, wn = (w >> 1) * 64;
  const int fr = lane & 15, quad = lane >> 4;

  f32x4 acc[4][4] = {};

  const int sr = lane >> 3;              // 0..7
  const int sc = ((lane & 7) - sr) & 7;  // rotated chunk
  const bf16* ga = A  + (size_t)(m0 + w * 32 + sr) * HID + sc * 8;
  const bf16* gb = Bt + (size_t)(n0 + w * 32 + sr) * HID + sc * 8;

  for (int k0 = 0; k0 < HID; k0 += 64) {
    __syncthreads();
    #pragma unroll
    for (int c = 0; c < 4; ++c) {
      gll16(ga + (size_t)(c * 8) * HID + k0, As + (w * 32 + c * 8) * 64);
      gll16(gb + (size_t)(c * 8) * HID + k0, Bs + (w * 32 + c * 8) * 64);
    }
    __syncthreads();
    #pragma unroll
    for (int ks = 0; ks < 2; ++ks) {
      bf16x8 af[4], bg[4];
      #pragma unroll
      for (int i = 0; i < 4; ++i)
        af[i] = *(const bf16x8*)&As[(wm + i * 16 + fr) * 64 +
                                    ((ks * 4 + quad + fr) & 7) * 8];
      #pragma unroll
      for (int i = 0; i < 4; ++i)
        bg[i] = *(const bf16x8*)&Bs[(wn + i * 16 + fr) * 64 +
                                    ((ks * 4 + quad + fr) & 7) * 8];
      #pragma unroll
      for (int mi = 0; mi < 4; ++mi)
        #pragma unroll
        for (int ni = 0; ni < 4; ++ni)
          acc[mi][ni] = __builtin_amdgcn_mfma_f32_16x16x32_bf16(
              af[mi], bg[ni], acc[mi][ni], 0, 0, 0);
    }
  }

  if (z < 2) {
    bf16* C = z ? Kg : Qg;
    #pragma unroll
    for (int mi = 0; mi < 4; ++mi)
      #pragma unroll
      for (int ni = 0; ni < 4; ++ni)
        #pragma unroll
        for (int r = 0; r < 4; ++r)
          C[(size_t)(m0 + wm + mi * 16 + quad * 4 + r) * HID +
            n0 + wn + ni * 16 + fr] = (bf16)acc[mi][ni][r];
  } else {
    __syncthreads();
    // swizzled transpose: col stored at (col + 8*(row&15)) & 127
    #pragma unroll
    for (int mi = 0; mi < 4; ++mi)
      #pragma unroll
      for (int ni = 0; ni < 4; ++ni)
        #pragma unroll
        for (int r = 0; r < 4; ++r) {
          int row = wn + ni * 16 + fr;
          int col = wm + mi * 16 + quad * 4 + r;
          int colS = (col + 8 * (row & 15)) & 127;
          sbuf[row * 128 + colS] = (bf16)acc[mi][ni][r];
        }
    __syncthreads();
    const int row = t >> 1, cb = (t & 1) * 64;
    #pragma unroll
    for (int j = 0; j < 8; ++j) {
      int c0 = (cb + j * 8 + 8 * (row & 15)) & 127;
      *(bf16x8*)&Vt[(size_t)(n0 + row) * SEQ + m0 + cb + j * 8] =
          *(const bf16x8*)&sbuf[row * 128 + c0];
    }
  }
}

// ---------------------------------------------------------------------------
// O-projection: out = Og[M,K] @ Wto[N,K]^T, fp32 out. Same swizzled staging.
// ---------------------------------------------------------------------------
__global__ __launch_bounds__(256)
void oproj_gemm(const bf16* __restrict__ A, const bf16* __restrict__ Bt,
                float* __restrict__ C)
{
  __shared__ bf16 sbuf[16384];
  bf16* As = sbuf;
  bf16* Bs = sbuf + 8192;

  const int t = threadIdx.x, lane = t & 63, w = t >> 6;
  const int n0 = blockIdx.x * 128, m0 = blockIdx.y * 128;
  const int wm = (w & 1) * 64, wn = (w >> 1) * 64;
  const int fr = lane & 15, quad = lane >> 4;

  f32x4 acc[4][4] = {};

  const int sr = lane >> 3;
  const int sc = ((lane & 7) - sr) & 7;
  const bf16* ga = A  + (size_t)(m0 + w * 32 + sr) * HID + sc * 8;
  const bf16* gb = Bt + (size_t)(n0 + w * 32 + sr) * HID + sc * 8;

  for (int k0 = 0; k0 < HID; k0 += 64) {
    __syncthreads();
    #pragma unroll
    for (int c = 0; c < 4; ++c) {
      gll16(ga + (size_t)(c * 8) * HID + k0, As + (w * 32 + c * 8) * 64);
      gll16(gb + (size_t)(c * 8) * HID + k0, Bs + (w * 32 + c * 8) * 64);
    }
    __syncthreads();
    #pragma unroll
    for (int ks = 0; ks < 2; ++ks) {
      bf16x8 af[4], bg[4];
      #pragma unroll
      for (int i = 0; i < 4; ++i)
        af[i] = *(const bf16x8*)&As[(wm + i * 16 + fr) * 64 +
                                    ((ks * 4 + quad + fr) & 7) * 8];
      #pragma unroll
      for (int i = 0; i < 4; ++i)
        bg[i] = *(const bf16x8*)&Bs[(wn + i * 16 + fr) * 64 +
                                    ((ks * 4 + quad + fr) & 7) * 8];
      #pragma unroll
      for (int mi = 0; mi < 4; ++mi)
        #pragma unroll
        for (int ni = 0; ni < 4; ++ni)
          acc[mi][ni] = __builtin_amdgcn_mfma_f32_16x16x32_bf16(
              af[mi], bg[ni], acc[mi][ni], 0, 0, 0);
    }
  }

  #pragma unroll
  for (int mi = 0; mi < 4; ++mi)
    #pragma unroll
    for (int ni = 0; ni < 4; ++ni)
      #pragma unroll
      for (int r = 0; r < 4; ++r)
        C[(size_t)(m0 + wm + mi * 16 + quad * 4 + r) * HID +
          n0 + wn + ni * 16 + fr] = acc[mi][ni][r];
}

// ---------------------------------------------------------------------------
// Attention v3: 32 q-rows/wave (wg = 128 q x 1 head), S^T = K.Q^T.
// K/V tiles double-buffered in LDS with chunk-rotation swizzle; one barrier
// per KV tile; P kept in wave-private swizzled LDS (bf16x4 writes).
// Per-1024-block local max via online rescale == reference semantics.
// ---------------------------------------------------------------------------
__global__ __launch_bounds__(256)
void attn3(const bf16* __restrict__ Q, const bf16* __restrict__ K,
           const bf16* __restrict__ Vt, bf16* __restrict__ O)
{
  __shared__ bf16 Ks[2][4096];
  __shared__ bf16 Vs[2][4096];
  __shared__ bf16 Ps[4][2048];

  const int t = threadIdx.x, lane = t & 63, w = t >> 6;
  const int h = blockIdx.y, q0 = blockIdx.x * 128;
  const int fr = lane & 15, quad = lane >> 4;

  // Q B-fragments (direct from global)
  bf16x8 bq[2][2];
  #pragma unroll
  for (int qf = 0; qf < 2; ++qf)
    #pragma unroll
    for (int ks = 0; ks < 2; ++ks)
      bq[qf][ks] = *(const bf16x8*)&Q[(size_t)(q0 + w * 32 + qf * 16 + fr) * HID
                                      + h * 64 + ks * 32 + quad * 8];

  const int sr = lane >> 3;
  const int sc = ((lane & 7) - sr) & 7;
  const bf16* gk = K  + (size_t)(w * 16 + sr) * HID + h * 64 + sc * 8;
  const bf16* gv = Vt + (size_t)(h * 64 + w * 16 + sr) * SEQ + sc * 8;

  #pragma unroll
  for (int j = 0; j < 2; ++j) {
    gll16(gk + (size_t)(j * 8) * HID, &Ks[0][(w * 16 + j * 8) * 64]);
    gll16(gv + (size_t)(j * 8) * SEQ, &Vs[0][(w * 16 + j * 8) * 64]);
  }

  f32x4 accN[2][4] = {};
  f32x4 accO[2][4] = {};
  float m_i[2] = {-3e38f, -3e38f}, l_i[2] = {0.f, 0.f}, den[2] = {0.f, 0.f};

  __syncthreads();

  for (int kk = 0; kk < 64; ++kk) {
    const int buf = kk & 1;
    if (kk < 63) {
      const size_t key0n = (size_t)(kk + 1) * 64;
      #pragma unroll
      for (int j = 0; j < 2; ++j) {
        gll16(gk + (key0n + j * 8) * HID, &Ks[buf ^ 1][(w * 16 + j * 8) * 64]);
        gll16(gv + key0n + (size_t)(j * 8) * SEQ,
              &Vs[buf ^ 1][(w * 16 + j * 8) * 64]);
      }
    }

    // K fragments (shared across both q-fragments)
    bf16x8 ak[4][2];
    #pragma unroll
    for (int mt = 0; mt < 4; ++mt)
      #pragma unroll
      for (int ks = 0; ks < 2; ++ks)
        ak[mt][ks] = *(const bf16x8*)&Ks[buf][(mt * 16 + fr) * 64 +
                                             ((ks * 4 + quad + fr) & 7) * 8];

    #pragma unroll
    for (int qf = 0; qf < 2; ++qf) {
      f32x4 s[4];
      #pragma unroll
      for (int mt = 0; mt < 4; ++mt) {
        f32x4 z = {};
        z = __builtin_amdgcn_mfma_f32_16x16x32_bf16(ak[mt][0], bq[qf][0], z, 0, 0, 0);
        z = __builtin_amdgcn_mfma_f32_16x16x32_bf16(ak[mt][1], bq[qf][1], z, 0, 0, 0);
        s[mt] = z;
      }
      float mx = -3e38f;
      #pragma unroll
      for (int mt = 0; mt < 4; ++mt)
        #pragma unroll
        for (int r = 0; r < 4; ++r) mx = fmaxf(mx, s[mt][r]);
      mx = fmaxf(mx, __shfl_xor(mx, 16));
      mx = fmaxf(mx, __shfl_xor(mx, 32));
      const float mnew = fmaxf(m_i[qf], mx);
      const float alpha = __expf(m_i[qf] - mnew);
      m_i[qf] = mnew;
      float sum = 0.f;
      const int prow = (qf * 16 + fr) * 64;
      #pragma unroll
      for (int mt = 0; mt < 4; ++mt) {
        float p0 = __expf(s[mt][0] - mnew);
        float p1 = __expf(s[mt][1] - mnew);
        float p2 = __expf(s[mt][2] - mnew);
        float p3 = __expf(s[mt][3] - mnew);
        sum += (p0 + p1) + (p2 + p3);
        bf16x4 pv = {(bf16)p0, (bf16)p1, (bf16)p2, (bf16)p3};
        *(bf16x4*)&Ps[w][prow + ((mt * 2 + (quad >> 1) + fr) & 7) * 8 +
                         (quad & 1) * 4] = pv;
      }
      sum += __shfl_xor(sum, 16);
      sum += __shfl_xor(sum, 32);
      l_i[qf] = l_i[qf] * alpha + sum;
      #pragma unroll
      for (int dt = 0; dt < 4; ++dt) accO[qf][dt] *= alpha;
    }

    // O^T += V^T . P^T
    #pragma unroll
    for (int ks = 0; ks < 2; ++ks) {
      bf16x8 bp0 = *(const bf16x8*)&Ps[w][fr * 64 +
                                          ((ks * 4 + quad + fr) & 7) * 8];
      bf16x8 bp1 = *(const bf16x8*)&Ps[w][(16 + fr) * 64 +
                                          ((ks * 4 + quad + fr) & 7) * 8];
      #pragma unroll
      for (int dt = 0; dt < 4; ++dt) {
        bf16x8 av = *(const bf16x8*)&Vs[buf][(dt * 16 + fr) * 64 +
                                            ((ks * 4 + quad + fr) & 7) * 8];
        accO[0][dt] = __builtin_amdgcn_mfma_f32_16x16x32_bf16(av, bp0, accO[0][dt], 0, 0, 0);
        accO[1][dt] = __builtin_amdgcn_mfma_f32_16x16x32_bf16(av, bp1, accO[1][dt], 0, 0, 0);
      }
    }

    if ((kk & 15) == 15) {   // end of 1024-key block: fold, reset local state
      #pragma unroll
      for (int qf = 0; qf < 2; ++qf) {
        #pragma unroll
        for (int dt = 0; dt < 4; ++dt) {
          #pragma unroll
          for (int r = 0; r < 4; ++r) accN[qf][dt][r] += accO[qf][dt][r];
          accO[qf][dt] = (f32x4){0.f, 0.f, 0.f, 0.f};
        }
        den[qf] += l_i[qf];
        l_i[qf] = 0.f;
        m_i[qf] = -3e38f;
      }
    }
    __syncthreads();
  }

  #pragma unroll
  for (int qf = 0; qf < 2; ++qf) {
    const float inv = 1.0f / den[qf];
    const size_t orow = (size_t)(q0 + w * 32 + qf * 16 + fr) * HID + h * 64;
    #pragma unroll
    for (int dt = 0; dt < 4; ++dt) {
      bf16x4 ov = {(bf16)(accN[qf][dt][0] * inv), (bf16)(accN[qf][dt][1] * inv),
                   (bf16)(accN[qf][dt][2] * inv), (bf16)(accN[qf][dt][3] * inv)};
      *(bf16x4*)&O[orow + dt * 16 + quad * 4] = ov;
    }
  }
}

extern "C" void kernel_launch(void* const* d_in, const int* in_sizes, int n_in,
                              void* d_out, int out_size, void* d_ws, size_t ws_size,
                              hipStream_t stream)
{
  const float* X  = (const float*)d_in[0];
  const float* Wq = (const float*)d_in[1];
  const float* Wk = (const float*)d_in[2];
  const float* Wv = (const float*)d_in[3];
  const float* Wo = (const float*)d_in[4];
  float* out = (float*)d_out;

  const size_t MB = 1024 * 1024;
  bf16* Xb  = (bf16*)d_ws;                       // 8 MB
  bf16* Wt  = (bf16*)((char*)d_ws + 8  * MB);    // 4 x 2 MB
  bf16* Qg  = (bf16*)((char*)d_ws + 16 * MB);    // 8 MB
  bf16* Kg  = (bf16*)((char*)d_ws + 24 * MB);    // 8 MB
  bf16* Vtg = (bf16*)((char*)d_ws + 32 * MB);    // 8 MB, [hid][seq]
  bf16* Og  = (bf16*)((char*)d_ws + 40 * MB);    // 8 MB

  prep_kernel<<<dim3(256, 1, 5), 256, 0, stream>>>(X, Wq, Wk, Wv, Wo, Xb, Wt);
  qkv_gemm<<<dim3(HID / 128, SEQ / 128, 3), 256, 0, stream>>>(Xb, Wt, Qg, Kg, Vtg);
  attn3<<<dim3(SEQ / 128, NHEADS), 256, 0, stream>>>(Qg, Kg, Vtg, Og);
  oproj_gemm<<<dim3(HID / 128, SEQ / 128), 256, 0, stream>>>(
      Og, Wt + (size_t)3 * HID * HID, out);
}

// Round 2
// 250.871 us; speedup vs baseline: 1.1001x; 1.1001x over previous
//
#include <hip/hip_runtime.h>
#include <hip/hip_bf16.h>

typedef __bf16 bf16;
typedef bf16 bf16x2 __attribute__((ext_vector_type(2)));
typedef bf16 bf16x4 __attribute__((ext_vector_type(4)));
typedef bf16 bf16x8 __attribute__((ext_vector_type(8)));
typedef float f32x4 __attribute__((ext_vector_type(4)));

#define HID 1024
#define NHEADS 16
#define HD 64
#define SEQ 4096

__device__ __forceinline__ void gll16(const void* g, void* l) {
  __builtin_amdgcn_global_load_lds(
      (const __attribute__((address_space(1))) void*)g,
      (__attribute__((address_space(3))) void*)l, 16, 0, 0);
}

__device__ __forceinline__ float fast_exp2(float x) {
#if __has_builtin(__builtin_amdgcn_exp2f)
  return __builtin_amdgcn_exp2f(x);
#else
  return __expf(x * 0.6931471805599453f);
#endif
}

// ---------------------------------------------------------------------------
// Prep: z=0 convert X fp32->bf16; z=1..4 transpose+convert W -> Wt[out][in].
// Attention scale folded into Wq in LOG2 domain: 0.125 * log2(e), so the
// softmax can use exp2 directly (saves one v_mul per P element).
// ---------------------------------------------------------------------------
__global__ __launch_bounds__(256)
void prep_kernel(const float* __restrict__ X,
                 const float* __restrict__ Wq, const float* __restrict__ Wk,
                 const float* __restrict__ Wv, const float* __restrict__ Wo,
                 bf16* __restrict__ Xb, bf16* __restrict__ Wt)
{
  const int z = blockIdx.z, t = threadIdx.x, bx = blockIdx.x;
  if (z == 0) {
    const float4* src = (const float4*)X;
    const int gid = bx * 256 + t;
    #pragma unroll
    for (int i = 0; i < 16; ++i) {
      float4 v = src[gid + i * 65536];
      bf16x4 o = {(bf16)v.x, (bf16)v.y, (bf16)v.z, (bf16)v.w};
      *(bf16x4*)&Xb[(size_t)(gid + i * 65536) * 4] = o;
    }
  } else {
    const float* W = (z == 1) ? Wq : (z == 2) ? Wk : (z == 3) ? Wv : Wo;
    bf16* dst = Wt + (size_t)(z - 1) * HID * HID;
    const float scale = (z == 1) ? 0.18033688011112042f : 1.0f;  // 0.125*log2(e)
    __shared__ bf16 T[64][68];
    const int tr = (bx >> 4) * 64, tc = (bx & 15) * 64;
    #pragma unroll
    for (int p = 0; p < 4; ++p) {
      int row = (t >> 4) + p * 16;
      float4 v = *(const float4*)&W[(size_t)(tr + row) * HID + tc + (t & 15) * 4];
      T[row][(t & 15) * 4 + 0] = (bf16)(v.x * scale);
      T[row][(t & 15) * 4 + 1] = (bf16)(v.y * scale);
      T[row][(t & 15) * 4 + 2] = (bf16)(v.z * scale);
      T[row][(t & 15) * 4 + 3] = (bf16)(v.w * scale);
    }
    __syncthreads();
    #pragma unroll
    for (int p = 0; p < 4; ++p) {
      int rp = (t >> 4) + p * 16;
      int cb = (t & 15) * 4;
      bf16x4 o = {T[cb + 0][rp], T[cb + 1][rp], T[cb + 2][rp], T[cb + 3][rp]};
      *(bf16x4*)&dst[(size_t)(tc + rp) * HID + tr + cb] = o;
    }
  }
}

// ---------------------------------------------------------------------------
// QKV GEMM: C = Xb[M,K] @ Wt[z][N,K]^T. 128x128 tile, BK=64, global_load_lds
// staging with chunk-rotation swizzle (row k chunk c -> slot k*8+((c+k)&7)).
// z=2 writes V transposed (Vt[hid][seq]) via swizzled LDS transpose.
// ---------------------------------------------------------------------------
__global__ __launch_bounds__(256)
void qkv_gemm(const bf16* __restrict__ A, const bf16* __restrict__ Wt,
              bf16* __restrict__ Qg, bf16* __restrict__ Kg,
              bf16* __restrict__ Vt)
{
  __shared__ bf16 sbuf[16384];
  bf16* As = sbuf;
  bf16* Bs = sbuf + 8192;

  const int t = threadIdx.x, lane = t & 63, w = t >> 6;
  const int z = blockIdx.z;
  const int n0 = blockIdx.x * 128, m0 = blockIdx.y * 128;
  const bf16* Bt = Wt + (size_t)z * HID * HID;
  const int wm = (w & 1) * 64, wn = (w >> 1) * 64;
  const int fr = lane & 15, quad = lane >> 4;

  f32x4 acc[4][4] = {};

  const int sr = lane >> 3;              // 0..7
  const int sc = ((lane & 7) - sr) & 7;  // rotated chunk
  const bf16* ga = A  + (size_t)(m0 + w * 32 + sr) * HID + sc * 8;
  const bf16* gb = Bt + (size_t)(n0 + w * 32 + sr) * HID + sc * 8;

  for (int k0 = 0; k0 < HID; k0 += 64) {
    __syncthreads();
    #pragma unroll
    for (int c = 0; c < 4; ++c) {
      gll16(ga + (size_t)(c * 8) * HID + k0, As + (w * 32 + c * 8) * 64);
      gll16(gb + (size_t)(c * 8) * HID + k0, Bs + (w * 32 + c * 8) * 64);
    }
    __syncthreads();
    #pragma unroll
    for (int ks = 0; ks < 2; ++ks) {
      bf16x8 af[4], bg[4];
      #pragma unroll
      for (int i = 0; i < 4; ++i)
        af[i] = *(const bf16x8*)&As[(wm + i * 16 + fr) * 64 +
                                    ((ks * 4 + quad + fr) & 7) * 8];
      #pragma unroll
      for (int i = 0; i < 4; ++i)
        bg[i] = *(const bf16x8*)&Bs[(wn + i * 16 + fr) * 64 +
                                    ((ks * 4 + quad + fr) & 7) * 8];
      #pragma unroll
      for (int mi = 0; mi < 4; ++mi)
        #pragma unroll
        for (int ni = 0; ni < 4; ++ni)
          acc[mi][ni] = __builtin_amdgcn_mfma_f32_16x16x32_bf16(
              af[mi], bg[ni], acc[mi][ni], 0, 0, 0);
    }
  }

  if (z < 2) {
    bf16* C = z ? Kg : Qg;
    #pragma unroll
    for (int mi = 0; mi < 4; ++mi)
      #pragma unroll
      for (int ni = 0; ni < 4; ++ni)
        #pragma unroll
        for (int r = 0; r < 4; ++r)
          C[(size_t)(m0 + wm + mi * 16 + quad * 4 + r) * HID +
            n0 + wn + ni * 16 + fr] = (bf16)acc[mi][ni][r];
  } else {
    __syncthreads();
    // swizzled transpose: col stored at (col + 8*(row&15)) & 127
    #pragma unroll
    for (int mi = 0; mi < 4; ++mi)
      #pragma unroll
      for (int ni = 0; ni < 4; ++ni)
        #pragma unroll
        for (int r = 0; r < 4; ++r) {
          int row = wn + ni * 16 + fr;
          int col = wm + mi * 16 + quad * 4 + r;
          int colS = (col + 8 * (row & 15)) & 127;
          sbuf[row * 128 + colS] = (bf16)acc[mi][ni][r];
        }
    __syncthreads();
    const int row = t >> 1, cb = (t & 1) * 64;
    #pragma unroll
    for (int j = 0; j < 8; ++j) {
      int c0 = (cb + j * 8 + 8 * (row & 15)) & 127;
      *(bf16x8*)&Vt[(size_t)(n0 + row) * SEQ + m0 + cb + j * 8] =
          *(const bf16x8*)&sbuf[row * 128 + c0];
    }
  }
}

// ---------------------------------------------------------------------------
// O-projection: out = Og[M,K] @ Wto[N,K]^T, fp32 out. Same swizzled staging.
// ---------------------------------------------------------------------------
__global__ __launch_bounds__(256)
void oproj_gemm(const bf16* __restrict__ A, const bf16* __restrict__ Bt,
                float* __restrict__ C)
{
  __shared__ bf16 sbuf[16384];
  bf16* As = sbuf;
  bf16* Bs = sbuf + 8192;

  const int t = threadIdx.x, lane = t & 63, w = t >> 6;
  const int n0 = blockIdx.x * 128, m0 = blockIdx.y * 128;
  const int wm = (w & 1) * 64, wn = (w >> 1) * 64;
  const int fr = lane & 15, quad = lane >> 4;

  f32x4 acc[4][4] = {};

  const int sr = lane >> 3;
  const int sc = ((lane & 7) - sr) & 7;
  const bf16* ga = A  + (size_t)(m0 + w * 32 + sr) * HID + sc * 8;
  const bf16* gb = Bt + (size_t)(n0 + w * 32 + sr) * HID + sc * 8;

  for (int k0 = 0; k0 < HID; k0 += 64) {
    __syncthreads();
    #pragma unroll
    for (int c = 0; c < 4; ++c) {
      gll16(ga + (size_t)(c * 8) * HID + k0, As + (w * 32 + c * 8) * 64);
      gll16(gb + (size_t)(c * 8) * HID + k0, Bs + (w * 32 + c * 8) * 64);
    }
    __syncthreads();
    #pragma unroll
    for (int ks = 0; ks < 2; ++ks) {
      bf16x8 af[4], bg[4];
      #pragma unroll
      for (int i = 0; i < 4; ++i)
        af[i] = *(const bf16x8*)&As[(wm + i * 16 + fr) * 64 +
                                    ((ks * 4 + quad + fr) & 7) * 8];
      #pragma unroll
      for (int i = 0; i < 4; ++i)
        bg[i] = *(const bf16x8*)&Bs[(wn + i * 16 + fr) * 64 +
                                    ((ks * 4 + quad + fr) & 7) * 8];
      #pragma unroll
      for (int mi = 0; mi < 4; ++mi)
        #pragma unroll
        for (int ni = 0; ni < 4; ++ni)
          acc[mi][ni] = __builtin_amdgcn_mfma_f32_16x16x32_bf16(
              af[mi], bg[ni], acc[mi][ni], 0, 0, 0);
    }
  }

  #pragma unroll
  for (int mi = 0; mi < 4; ++mi)
    #pragma unroll
    for (int ni = 0; ni < 4; ++ni)
      #pragma unroll
      for (int r = 0; r < 4; ++r)
        C[(size_t)(m0 + wm + mi * 16 + quad * 4 + r) * HID +
          n0 + wn + ni * 16 + fr] = acc[mi][ni][r];
}

// ---------------------------------------------------------------------------
// Attention v4: 8 waves x 16 q-rows (wg = 128 q x 1 head), S^T = K.Q^T.
// - 512 threads, 48 KiB LDS -> 2 blocks/CU = 16 waves/CU (2x v3 occupancy).
// - exp2-domain softmax (log2e folded into Wq).
// - deferred rescale: P = exp2(s - m_used) with m_used bumped only when the
//   tile max exceeds it by >12; exact block-max semantics restored at each
//   1024-key block end via c = exp2(m_used - m_true).
// ---------------------------------------------------------------------------
#define THR_L2 12.0f

__global__ __launch_bounds__(512, 4)
void attn4(const bf16* __restrict__ Q, const bf16* __restrict__ K,
           const bf16* __restrict__ Vt, bf16* __restrict__ O)
{
  __shared__ bf16 Ks[2][4096];
  __shared__ bf16 Vs[2][4096];
  __shared__ bf16 Ps[8][1024];

  const int t = threadIdx.x, lane = t & 63, w = t >> 6;
  const int h = blockIdx.y, q0 = blockIdx.x * 128;
  const int fr = lane & 15, quad = lane >> 4;

  // Q B-fragments (direct from global)
  bf16x8 bq[2];
  #pragma unroll
  for (int ks = 0; ks < 2; ++ks)
    bq[ks] = *(const bf16x8*)&Q[(size_t)(q0 + w * 16 + fr) * HID
                                + h * 64 + ks * 32 + quad * 8];

  const int sr = lane >> 3;
  const int sc = ((lane & 7) - sr) & 7;
  const bf16* gk = K  + (size_t)(w * 8 + sr) * HID + h * 64 + sc * 8;
  const bf16* gv = Vt + (size_t)(h * 64 + w * 8 + sr) * SEQ + sc * 8;

  gll16(gk, &Ks[0][(w * 8) * 64]);
  gll16(gv, &Vs[0][(w * 8) * 64]);

  f32x4 accN[4] = {};
  f32x4 accO[4] = {};
  float m_used = -3e38f, m_true = -3e38f, l_i = 0.f, den = 0.f;

  __syncthreads();

  for (int kk = 0; kk < 64; ++kk) {
    const int buf = kk & 1;
    if (kk < 63) {
      const size_t key0n = (size_t)(kk + 1) * 64;
      gll16(gk + key0n * HID, &Ks[buf ^ 1][(w * 8) * 64]);
      gll16(gv + key0n,       &Vs[buf ^ 1][(w * 8) * 64]);
    }

    // K fragments
    bf16x8 ak[4][2];
    #pragma unroll
    for (int mt = 0; mt < 4; ++mt)
      #pragma unroll
      for (int ks = 0; ks < 2; ++ks)
        ak[mt][ks] = *(const bf16x8*)&Ks[buf][(mt * 16 + fr) * 64 +
                                             ((ks * 4 + quad + fr) & 7) * 8];

    f32x4 s[4];
    #pragma unroll
    for (int mt = 0; mt < 4; ++mt) {
      f32x4 z = {};
      z = __builtin_amdgcn_mfma_f32_16x16x32_bf16(ak[mt][0], bq[0], z, 0, 0, 0);
      z = __builtin_amdgcn_mfma_f32_16x16x32_bf16(ak[mt][1], bq[1], z, 0, 0, 0);
      s[mt] = z;
    }

    // tile max per q-row (lane fr), reduced across quads
    float mx0 = fmaxf(fmaxf(s[0][0], s[0][1]), fmaxf(s[0][2], s[0][3]));
    float mx1 = fmaxf(fmaxf(s[1][0], s[1][1]), fmaxf(s[1][2], s[1][3]));
    float mx2 = fmaxf(fmaxf(s[2][0], s[2][1]), fmaxf(s[2][2], s[2][3]));
    float mx3 = fmaxf(fmaxf(s[3][0], s[3][1]), fmaxf(s[3][2], s[3][3]));
    float mx = fmaxf(fmaxf(mx0, mx1), fmaxf(mx2, mx3));
    mx = fmaxf(mx, __shfl_xor(mx, 16));
    mx = fmaxf(mx, __shfl_xor(mx, 32));
    m_true = fmaxf(m_true, mx);

    if (__any(mx > m_used + THR_L2)) {   // rare: bump m_used, rescale state
      const float mn = fmaxf(m_used, mx);
      const float a = fast_exp2(m_used - mn);
      m_used = mn;
      l_i *= a;
      #pragma unroll
      for (int dt = 0; dt < 4; ++dt) accO[dt] *= a;
    }

    float sum = 0.f;
    const int prow = fr * 64;
    #pragma unroll
    for (int mt = 0; mt < 4; ++mt) {
      float p0 = fast_exp2(s[mt][0] - m_used);
      float p1 = fast_exp2(s[mt][1] - m_used);
      float p2 = fast_exp2(s[mt][2] - m_used);
      float p3 = fast_exp2(s[mt][3] - m_used);
      sum += (p0 + p1) + (p2 + p3);
      bf16x4 pv = {(bf16)p0, (bf16)p1, (bf16)p2, (bf16)p3};
      *(bf16x4*)&Ps[w][prow + ((mt * 2 + (quad >> 1) + fr) & 7) * 8 +
                       (quad & 1) * 4] = pv;
    }
    sum += __shfl_xor(sum, 16);
    sum += __shfl_xor(sum, 32);
    l_i += sum;

    // O^T += V^T . P^T
    #pragma unroll
    for (int ks = 0; ks < 2; ++ks) {
      bf16x8 bp = *(const bf16x8*)&Ps[w][fr * 64 +
                                         ((ks * 4 + quad + fr) & 7) * 8];
      #pragma unroll
      for (int dt = 0; dt < 4; ++dt) {
        bf16x8 av = *(const bf16x8*)&Vs[buf][(dt * 16 + fr) * 64 +
                                            ((ks * 4 + quad + fr) & 7) * 8];
        accO[dt] = __builtin_amdgcn_mfma_f32_16x16x32_bf16(av, bp, accO[dt], 0, 0, 0);
      }
    }

    if ((kk & 15) == 15) {   // end of 1024-key block: exact local-max fold
      const float c = fast_exp2(m_used - m_true);
      den += l_i * c;
      #pragma unroll
      for (int dt = 0; dt < 4; ++dt)
        #pragma unroll
        for (int r = 0; r < 4; ++r) accN[dt][r] += accO[dt][r] * c;
      #pragma unroll
      for (int dt = 0; dt < 4; ++dt) accO[dt] = (f32x4){0.f, 0.f, 0.f, 0.f};
      l_i = 0.f; m_used = -3e38f; m_true = -3e38f;
    }
    __syncthreads();
  }

  const float inv = 1.0f / den;
  const size_t orow = (size_t)(q0 + w * 16 + fr) * HID + h * 64;
  #pragma unroll
  for (int dt = 0; dt < 4; ++dt) {
    bf16x4 ov = {(bf16)(accN[dt][0] * inv), (bf16)(accN[dt][1] * inv),
                 (bf16)(accN[dt][2] * inv), (bf16)(accN[dt][3] * inv)};
    *(bf16x4*)&O[orow + dt * 16 + quad * 4] = ov;
  }
}

extern "C" void kernel_launch(void* const* d_in, const int* in_sizes, int n_in,
                              void* d_out, int out_size, void* d_ws, size_t ws_size,
                              hipStream_t stream)
{
  const float* X  = (const float*)d_in[0];
  const float* Wq = (const float*)d_in[1];
  const float* Wk = (const float*)d_in[2];
  const float* Wv = (const float*)d_in[3];
  const float* Wo = (const float*)d_in[4];
  float* out = (float*)d_out;

  const size_t MB = 1024 * 1024;
  bf16* Xb  = (bf16*)d_ws;                       // 8 MB
  bf16* Wt  = (bf16*)((char*)d_ws + 8  * MB);    // 4 x 2 MB
  bf16* Qg  = (bf16*)((char*)d_ws + 16 * MB);    // 8 MB
  bf16* Kg  = (bf16*)((char*)d_ws + 24 * MB);    // 8 MB
  bf16* Vtg = (bf16*)((char*)d_ws + 32 * MB);    // 8 MB, [hid][seq]
  bf16* Og  = (bf16*)((char*)d_ws + 40 * MB);    // 8 MB

  prep_kernel<<<dim3(256, 1, 5), 256, 0, stream>>>(X, Wq, Wk, Wv, Wo, Xb, Wt);
  qkv_gemm<<<dim3(HID / 128, SEQ / 128, 3), 256, 0, stream>>>(Xb, Wt, Qg, Kg, Vtg);
  attn4<<<dim3(SEQ / 128, NHEADS), 512, 0, stream>>>(Qg, Kg, Vtg, Og);
  oproj_gemm<<<dim3(HID / 128, SEQ / 128), 256, 0, stream>>>(
      Og, Wt + (size_t)3 * HID * HID, out);
}